// Round 1
// 263.279 us; speedup vs baseline: 1.1187x; 1.1187x over previous
//
#include <hip/hip_runtime.h>
#include <math.h>

#define W 128
#define NANG 128
#define SZ 128
#define NV 8
#define NROWS 2048          // B*C*H
#define K_DIM 1024          // NV * W
#define NPIX 16384          // SZ * SZ
#define OUT_SCALE 0.012271846303085130f   // pi / 256

typedef _Float16 f16x8 __attribute__((ext_vector_type(8)));
typedef _Float16 f16x4 __attribute__((ext_vector_type(4)));
typedef float    f32x4 __attribute__((ext_vector_type(4)));

// ws layout:
//   [0, 512)        : filter taps kt[128] f32
//   [512, 1536)     : cos/sin table float2[128]
//   [4096, 36864)   : Cf16 circulant [t][s] f16 128x128 (32 KiB)
//   [36864, +4MiB)  : Pf  f16 [2048 r][8 v][128 t]
//   [.., +32MiB)    : Wv  f16 [16384 pix][1024 k]
#define CF_OFF 4096
#define PF_OFF 36864
#define WV_OFF (36864 + (size_t)NROWS * K_DIM * 2)

struct Ptrs8 { const float* p[8]; };

__device__ __forceinline__ void glds16(const void* g, void* l) {
    __builtin_amdgcn_global_load_lds(
        (const __attribute__((address_space(1))) void*)g,
        (__attribute__((address_space(3))) void*)l, 16, 0, 0);
}

// ---- kernel 0: filter taps + trig tables + f16 circulant matrix ----
// kt[d] = (1/W^2) * [ 2*sum_{f=1..63} f*cos(2*pi*f*d/W) + 64*cos(pi*d) ]
__global__ void k_tables(float* __restrict__ kt, float2* __restrict__ cs,
                         _Float16* __restrict__ cf) {
    __shared__ float kl[W];
    int d = threadIdx.x;
    const float w0 = 6.283185307179586f / (float)W * (float)d;
    float s = 0.f;
    for (int f = 1; f < 64; ++f)
        s = fmaf((float)f, __cosf(w0 * (float)f), s);
    s = 2.f * s + 64.f * ((d & 1) ? -1.f : 1.f);
    float kv = s * (1.f / (float)(W * W));
    kt[d] = kv;
    kl[d] = kv;
    float th = (float)d * ((float)M_PI / (float)NANG);
    cs[d] = make_float2(cosf(th), sinf(th));
    __syncthreads();
    // Cf16[t][s] = kt[(t-s)&127], row t = thread d
    for (int k = 0; k < W; ++k)
        cf[d * W + k] = (_Float16)kl[(d - k) & (W - 1)];
}

// ---- kernel 1: filter as MFMA GEMM with fused f32->f16 cast ----
// Pf[(r,v)][t] = sum_s In[v][r][s] * C[t][s].  Grid: 256 blocks, 64 rows each.
// Tile rows: m = blk*64 + i*8 + v  ->  r = blk*8 + i (i=0..7), v=0..7.
#define FS_A 136   // padded LDS row stride (halfs): +8 -> 2-way bank alias only
__global__ __launch_bounds__(256)
void k_fgemm(Ptrs8 in, const _Float16* __restrict__ cf,
             _Float16* __restrict__ pf) {
    __shared__ _Float16 sA[64 * FS_A];
    __shared__ _Float16 sB[128 * FS_A];
    const int tid  = threadIdx.x;
    const int lane = tid & 63, wave = tid >> 6;
    const int fr = lane & 15, fg = lane >> 4;
    const int blk = blockIdx.x;

    // stage A: per view v, 8 rows x 128 f32 -> f16
    {
        const int i   = tid >> 5;          // row-within-view-group 0..7
        const int pos = (tid & 31) * 4;    // f32 position 0..124
#pragma unroll
        for (int v = 0; v < NV; ++v) {
            float4 x = *(const float4*)(in.p[v] + (size_t)(blk * 8 + i) * W + pos);
            f16x4 h = { (_Float16)x.x, (_Float16)x.y, (_Float16)x.z, (_Float16)x.w };
            *(f16x4*)&sA[(i * 8 + v) * FS_A + pos] = h;
        }
    }
    // stage B: circulant 128x128 f16, padded rows
#pragma unroll
    for (int j = 0; j < 8; ++j) {
        int c = tid + 256 * j;             // 2048 chunks of 8 halfs
        int n = c >> 4, kp = (c & 15) * 8;
        *(f16x8*)&sB[n * FS_A + kp] = *(const f16x8*)&cf[n * W + kp];
    }
    __syncthreads();

    f32x4 acc[8] = {};
#pragma unroll
    for (int kb = 0; kb < W; kb += 32) {
        f16x8 af = *(const f16x8*)&sA[(wave * 16 + fr) * FS_A + kb + fg * 8];
#pragma unroll
        for (int nt = 0; nt < 8; ++nt) {
            f16x8 bf = *(const f16x8*)&sB[(nt * 16 + fr) * FS_A + kb + fg * 8];
            acc[nt] = __builtin_amdgcn_mfma_f32_16x16x32_f16(af, bf, acc[nt], 0, 0, 0);
        }
    }
    // C/D: col = fr (t), row = fg*4 + rr (m within 16)
#pragma unroll
    for (int nt = 0; nt < 8; ++nt) {
        int m = blk * 64 + wave * 16 + fg * 4;
        int n = nt * 16 + fr;
#pragma unroll
        for (int rr = 0; rr < 4; ++rr)
            pf[(size_t)(m + rr) * W + n] = (_Float16)acc[nt][rr];
    }
}

// ---- kernel 2: build Wv[pixel][k] : fused angle-lerp x detector-lerp weights ----
__global__ void k_wv(const float2* __restrict__ cs, _Float16* __restrict__ wv) {
    __shared__ float wrow[8 * K_DIM];
    const int tid = threadIdx.x;
    const int p0 = blockIdx.x * 8;
    for (int i = tid; i < 8 * K_DIM; i += 256) wrow[i] = 0.f;
    __syncthreads();
    const int px  = tid >> 5;
    const int sub = tid & 31;
    const int p = p0 + px;
    const float x = (float)(p & 127) - 63.5f;
    const float y = (float)(p >> 7) - 63.5f;
    float* prow = &wrow[px * K_DIM];
    for (int a = sub; a < NANG; a += 32) {
        float2 c = cs[a];
        float t = fmaf(x, c.x, fmaf(y, c.y, 63.5f));
        t = fminf(fmaxf(t, 0.f), 127.f);
        float tf = fminf(floorf(t), 126.f);
        int   ti = (int)tf;
        float wt = t - tf;
        float src = ((float)a + 0.5f) * 0.0625f - 0.5f;
        src = fminf(fmaxf(src, 0.f), 7.f);
        float vf = floorf(src);
        int   v0 = (int)vf;
        int   v1 = v0 + 1 < NV ? v0 + 1 : NV - 1;
        float wa = src - vf;
        float wA0 = (1.f - wa) * OUT_SCALE;
        atomicAdd(&prow[v0 * W + ti],     wA0 * (1.f - wt));
        atomicAdd(&prow[v0 * W + ti + 1], wA0 * wt);
        if (v1 != v0) {
            float wA1 = wa * OUT_SCALE;
            atomicAdd(&prow[v1 * W + ti],     wA1 * (1.f - wt));
            atomicAdd(&prow[v1 * W + ti + 1], wA1 * wt);
        }
    }
    __syncthreads();
    // packed 2x f16 stores; block's 8192 elements are contiguous at wv + p0*K
    uint* wvu = (uint*)(wv + (size_t)p0 * K_DIM);
#pragma unroll
    for (int j = 0; j < 16; ++j) {
        int j2 = tid + 256 * j;
        float2 w2 = *(const float2*)&wrow[j2 * 2];
        union { uint u; struct { _Float16 lo, hi; } h; } pk;
        pk.h.lo = (_Float16)w2.x; pk.h.hi = (_Float16)w2.y;
        wvu[j2] = pk.u;
    }
}

// ---- kernel 3: 256x256-tile 8-phase pipelined GEMM ----
// Out[m][n] = sum_k Pf[m][k] * Wv[n][k].  M=2048, N=16384, K=1024.
// 512 threads = 8 waves (2M x 4N), per-wave 128x64 output, BK=64, NT=16.
// LDS 128 KiB: 2 buffers x (A 32K | B 32K).  XOR swizzle q^= row&7 on both
// write-source and read (glds dest stays linear).  One vmcnt(4) per K-tile.
#define NT 16

__device__ __forceinline__ void fencebar() {
    asm volatile("" ::: "memory");
    __builtin_amdgcn_s_barrier();
    asm volatile("" ::: "memory");
}

// Stage one half-tile (128 rows x 64 halfs = 16 KiB) of matrix G (row-major
// [rows][K_DIM]) into LDS region L (linear [256][64] halfs), rows h*128..h*128+127,
// K columns kt*64..kt*64+63.  2 glds16 per thread.  Global source is
// inverse-swizzled so reads can apply q ^= (row&7).
__device__ __forceinline__ void stage_half(const _Float16* __restrict__ G, int R0,
                                           int h, int kt, _Float16* L, int tid) {
#pragma unroll
    for (int r = 0; r < 2; ++r) {
        const int c   = r * 512 + tid;            // chunk 0..1023 (16 B each)
        const int row = (h << 7) + (c >> 3);
        const int q   = c & 7;
        const _Float16* src = G + (size_t)(R0 + row) * K_DIM + kt * 64
                                + ((q ^ (row & 7)) << 3);
        _Float16* dst = L + (h << 13) + ((r * 512 + (tid & 448)) << 3); // wave-uniform
        glds16(src, dst);
    }
}

__device__ __forceinline__ f16x8 frag(const _Float16* L, int row, int q) {
    return *(const f16x8*)(L + row * 64 + ((q ^ (row & 7)) << 3));
}

__global__ __launch_bounds__(512, 2)
void k_gemm(const _Float16* __restrict__ A,
            const _Float16* __restrict__ Bm,
            float* __restrict__ out) {
    __shared__ _Float16 lds[65536];   // 128 KiB
    const int tid  = threadIdx.x;
    const int lane = tid & 63, wid = tid >> 6;
    const int wm = wid >> 2, wn = wid & 3;
    const int fr = lane & 15, fg = lane >> 4;

    // bijective XCD swizzle (512 blocks % 8 == 0): XCD k owns M-band k.
    const int flat = blockIdx.y * 64 + blockIdx.x;
    const int swz  = (flat & 7) * 64 + (flat >> 3);
    const int m0 = (swz >> 6) * 256;
    const int n0 = (swz & 63) * 256;

    _Float16* const A0 = lds;
    _Float16* const B0 = lds + 16384;
    _Float16* const A1 = lds + 32768;
    _Float16* const B1 = lds + 49152;

    // prologue: tile0 all 4 halves + tile1 B-lo, A-lo  (12 loads/thread)
    stage_half(Bm, n0, 0, 0, B0, tid);
    stage_half(A,  m0, 0, 0, A0, tid);
    stage_half(Bm, n0, 1, 0, B0, tid);
    stage_half(A,  m0, 1, 0, A0, tid);
    stage_half(Bm, n0, 0, 1, B1, tid);
    stage_half(A,  m0, 0, 1, A1, tid);
    asm volatile("s_waitcnt vmcnt(4)" ::: "memory");  // tile0 landed; tile1 lo in flight
    fencebar();

    f32x4 acc[8][4] = {};
    f16x8 af[4][2], bf[4][2];
    const int ar = wm * 128 + fr;
    const int br = wn * 64 + fr;

    // per K-tile: 4 phases.  Stage slots (safety: issue only after the last
    // reader's barrier): P1->t+1 B-hi, P2->t+1 A-hi, P3->t+2 B-lo (B-lo of
    // buf[t&1] last read P2), P4->t+2 A-lo (A-lo last read P3).
    auto tile = [&](int t, _Float16* Ab, _Float16* Bb, _Float16* An, _Float16* Bn)
        __attribute__((always_inline)) {
        // ---- P1: read A m0-3 (8) + B n0-1 (4); MFMA m0-3 x n0-1 ----
#pragma unroll
        for (int i = 0; i < 4; ++i) {
            af[i][0] = frag(Ab, ar + i * 16, fg);
            af[i][1] = frag(Ab, ar + i * 16, 4 + fg);
        }
#pragma unroll
        for (int j = 0; j < 2; ++j) {
            bf[j][0] = frag(Bb, br + j * 16, fg);
            bf[j][1] = frag(Bb, br + j * 16, 4 + fg);
        }
        if (t + 1 < NT) stage_half(Bm, n0, 1, t + 1, Bn, tid);
        fencebar();
        asm volatile("s_waitcnt lgkmcnt(0)" ::: "memory");
        __builtin_amdgcn_sched_barrier(0);
        __builtin_amdgcn_s_setprio(1);
#pragma unroll
        for (int i = 0; i < 4; ++i)
#pragma unroll
            for (int j = 0; j < 2; ++j) {
                acc[i][j] = __builtin_amdgcn_mfma_f32_16x16x32_f16(af[i][0], bf[j][0], acc[i][j], 0, 0, 0);
                acc[i][j] = __builtin_amdgcn_mfma_f32_16x16x32_f16(af[i][1], bf[j][1], acc[i][j], 0, 0, 0);
            }
        __builtin_amdgcn_s_setprio(0);
        fencebar();
        // ---- P2: read B n2-3 (4); MFMA m0-3 x n2-3 ----
#pragma unroll
        for (int j = 2; j < 4; ++j) {
            bf[j][0] = frag(Bb, br + j * 16, fg);
            bf[j][1] = frag(Bb, br + j * 16, 4 + fg);
        }
        if (t + 1 < NT) stage_half(A, m0, 1, t + 1, An, tid);
        fencebar();
        asm volatile("s_waitcnt lgkmcnt(0)" ::: "memory");
        __builtin_amdgcn_sched_barrier(0);
        __builtin_amdgcn_s_setprio(1);
#pragma unroll
        for (int i = 0; i < 4; ++i)
#pragma unroll
            for (int j = 2; j < 4; ++j) {
                acc[i][j] = __builtin_amdgcn_mfma_f32_16x16x32_f16(af[i][0], bf[j][0], acc[i][j], 0, 0, 0);
                acc[i][j] = __builtin_amdgcn_mfma_f32_16x16x32_f16(af[i][1], bf[j][1], acc[i][j], 0, 0, 0);
            }
        __builtin_amdgcn_s_setprio(0);
        fencebar();
        // ---- P3: read A m4-7 (8); MFMA m4-7 x n2-3 ----
#pragma unroll
        for (int i = 0; i < 4; ++i) {
            af[i][0] = frag(Ab, ar + 64 + i * 16, fg);
            af[i][1] = frag(Ab, ar + 64 + i * 16, 4 + fg);
        }
        if (t + 2 < NT) stage_half(Bm, n0, 0, t + 2, Bb, tid);
        fencebar();
        asm volatile("s_waitcnt lgkmcnt(0)" ::: "memory");
        __builtin_amdgcn_sched_barrier(0);
        __builtin_amdgcn_s_setprio(1);
#pragma unroll
        for (int i = 0; i < 4; ++i)
#pragma unroll
            for (int j = 2; j < 4; ++j) {
                acc[4 + i][j] = __builtin_amdgcn_mfma_f32_16x16x32_f16(af[i][0], bf[j][0], acc[4 + i][j], 0, 0, 0);
                acc[4 + i][j] = __builtin_amdgcn_mfma_f32_16x16x32_f16(af[i][1], bf[j][1], acc[4 + i][j], 0, 0, 0);
            }
        __builtin_amdgcn_s_setprio(0);
        fencebar();
        // ---- P4: no reads; MFMA m4-7 x n0-1; counted tile-end wait ----
        if (t + 2 < NT) stage_half(A, m0, 0, t + 2, Ab, tid);
        fencebar();
        __builtin_amdgcn_s_setprio(1);
#pragma unroll
        for (int i = 0; i < 4; ++i)
#pragma unroll
            for (int j = 0; j < 2; ++j) {
                acc[4 + i][j] = __builtin_amdgcn_mfma_f32_16x16x32_f16(af[i][0], bf[j][0], acc[4 + i][j], 0, 0, 0);
                acc[4 + i][j] = __builtin_amdgcn_mfma_f32_16x16x32_f16(af[i][1], bf[j][1], acc[4 + i][j], 0, 0, 0);
            }
        __builtin_amdgcn_s_setprio(0);
        if (t + 2 < NT)      asm volatile("s_waitcnt vmcnt(4)" ::: "memory");
        else if (t + 1 < NT) asm volatile("s_waitcnt vmcnt(0)" ::: "memory");
        fencebar();
    };

    for (int tt = 0; tt < NT; tt += 2) {
        tile(tt,     A0, B0, A1, B1);
        tile(tt + 1, A1, B1, A0, B0);
    }

    // epilogue: C/D col = fr (n), row = fg*4 + rr (m within 16)
#pragma unroll
    for (int i = 0; i < 8; ++i) {
#pragma unroll
        for (int j = 0; j < 4; ++j) {
            const int m = m0 + wm * 128 + i * 16 + fg * 4;
            const int n = n0 + wn * 64 + j * 16 + fr;
            float* op = out + (size_t)m * NPIX + n;
#pragma unroll
            for (int rr = 0; rr < 4; ++rr)
                op[(size_t)rr * NPIX] = acc[i][j][rr];
        }
    }
}

extern "C" void kernel_launch(void* const* d_in, const int* in_sizes, int n_in,
                              void* d_out, int out_size, void* d_ws, size_t ws_size,
                              hipStream_t stream) {
    float*      kt = (float*)d_ws;
    float2*     cs = (float2*)((char*)d_ws + 512);
    _Float16*   cf = (_Float16*)((char*)d_ws + CF_OFF);
    _Float16*   pf = (_Float16*)((char*)d_ws + PF_OFF);
    _Float16*   wv = (_Float16*)((char*)d_ws + WV_OFF);

    Ptrs8 in;
    for (int i = 0; i < NV; ++i) in.p[i] = (const float*)d_in[i];

    k_tables<<<1, 128, 0, stream>>>(kt, cs, cf);
    k_fgemm<<<NROWS * NV / 64, 256, 0, stream>>>(in, cf, pf);
    k_wv<<<NPIX / 8, 256, 0, stream>>>(cs, wv);
    dim3 grid(NPIX / 256, NROWS / 256);   // 64 x 8 = 512 blocks
    k_gemm<<<grid, 512, 0, stream>>>(pf, wv, (float*)d_out);
}

// Round 2
// 261.637 us; speedup vs baseline: 1.1257x; 1.0063x over previous
//
#include <hip/hip_runtime.h>
#include <math.h>

#define W 128
#define NANG 128
#define SZ 128
#define NV 8
#define NROWS 2048          // B*C*H
#define K_DIM 1024          // NV * W
#define NPIX 16384          // SZ * SZ
#define OUT_SCALE 0.012271846303085130f   // pi / 256

typedef _Float16 f16x8 __attribute__((ext_vector_type(8)));
typedef _Float16 f16x4 __attribute__((ext_vector_type(4)));
typedef float    f32x4 __attribute__((ext_vector_type(4)));

// ws layout:
//   [36864, +4MiB)  : Pf  f16 [2048 r][8 v][128 t]
//   [.., +32MiB)    : Wv  f16 [16384 pix][1024 k]
#define PF_OFF 36864
#define WV_OFF (36864 + (size_t)NROWS * K_DIM * 2)

struct Ptrs8 { const float* p[8]; };

__device__ __forceinline__ void glds16(const void* g, void* l) {
    __builtin_amdgcn_global_load_lds(
        (const __attribute__((address_space(1))) void*)g,
        (__attribute__((address_space(3))) void*)l, 16, 0, 0);
}

// ---- kernel 1: fused prep ----
// blocks [0,256): filter-GEMM  Pf[(r,v)][t] = sum_s In[v][r][s] * C[t][s]
//   with the circulant C built in LDS from locally-computed filter taps.
// blocks [256,2304): Wv[pixel][k] fused angle-lerp x detector-lerp weights,
//   with the cos/sin table computed locally.
// Numerics identical to the previous 3-kernel version (same expressions).
#define FS_A 136   // padded LDS row stride (halfs): +8 -> 2-way bank alias only
#define PREP_FG_BLOCKS 256

union PrepLds {
    struct {                        // fgemm role (52.7 KB)
        _Float16 sA[64 * FS_A];
        _Float16 sB[128 * FS_A];
        float    kl[W];
    } fg;
    struct {                        // wv role (33.8 KB)
        float  wrow[8 * K_DIM];
        float2 cst[NANG];
    } wv;
};

__global__ __launch_bounds__(256)
void k_prep(Ptrs8 in, _Float16* __restrict__ pf, _Float16* __restrict__ wv) {
    __shared__ PrepLds u;
    const int tid = threadIdx.x;

    if (blockIdx.x < PREP_FG_BLOCKS) {
        // ================= filter-GEMM role =================
        const int blk  = blockIdx.x;
        const int lane = tid & 63, wave = tid >> 6;
        const int fr = lane & 15, fg = lane >> 4;

        // filter taps kt[d] = (1/W^2)*[2*sum_{f=1..63} f*cos(2pi f d/W) + 64*cos(pi d)]
        if (tid < W) {
            const int d = tid;
            const float w0 = 6.283185307179586f / (float)W * (float)d;
            float s = 0.f;
            for (int f = 1; f < 64; ++f)
                s = fmaf((float)f, __cosf(w0 * (float)f), s);
            s = 2.f * s + 64.f * ((d & 1) ? -1.f : 1.f);
            u.fg.kl[d] = s * (1.f / (float)(W * W));
        }
        // stage A: per view v, 8 rows x 128 f32 -> f16
        {
            const int i   = tid >> 5;          // row-within-view-group 0..7
            const int pos = (tid & 31) * 4;    // f32 position 0..124
#pragma unroll
            for (int v = 0; v < NV; ++v) {
                float4 x = *(const float4*)(in.p[v] + (size_t)(blk * 8 + i) * W + pos);
                f16x4 h = { (_Float16)x.x, (_Float16)x.y, (_Float16)x.z, (_Float16)x.w };
                *(f16x4*)&u.fg.sA[(i * 8 + v) * FS_A + pos] = h;
            }
        }
        __syncthreads();
        // build circulant C[t][s] = kl[(t-s)&127] into padded sB
        for (int e = tid; e < W * W; e += 256) {
            const int t = e >> 7, s = e & 127;
            u.fg.sB[t * FS_A + s] = (_Float16)u.fg.kl[(t - s) & (W - 1)];
        }
        __syncthreads();

        f32x4 acc[8] = {};
#pragma unroll
        for (int kb = 0; kb < W; kb += 32) {
            f16x8 af = *(const f16x8*)&u.fg.sA[(wave * 16 + fr) * FS_A + kb + fg * 8];
#pragma unroll
            for (int nt = 0; nt < 8; ++nt) {
                f16x8 bf = *(const f16x8*)&u.fg.sB[(nt * 16 + fr) * FS_A + kb + fg * 8];
                acc[nt] = __builtin_amdgcn_mfma_f32_16x16x32_f16(af, bf, acc[nt], 0, 0, 0);
            }
        }
        // C/D: col = fr (t), row = fg*4 + rr (m within 16)
#pragma unroll
        for (int nt = 0; nt < 8; ++nt) {
            int m = blk * 64 + wave * 16 + fg * 4;
            int n = nt * 16 + fr;
#pragma unroll
            for (int rr = 0; rr < 4; ++rr)
                pf[(size_t)(m + rr) * W + n] = (_Float16)acc[nt][rr];
        }
    } else {
        // ================= Wv role =================
        const int p0 = (blockIdx.x - PREP_FG_BLOCKS) * 8;
        if (tid < NANG) {
            float th = (float)tid * ((float)M_PI / (float)NANG);
            u.wv.cst[tid] = make_float2(cosf(th), sinf(th));
        }
        for (int i = tid; i < 8 * K_DIM; i += 256) u.wv.wrow[i] = 0.f;
        __syncthreads();
        const int px  = tid >> 5;
        const int sub = tid & 31;
        const int p = p0 + px;
        const float x = (float)(p & 127) - 63.5f;
        const float y = (float)(p >> 7) - 63.5f;
        float* prow = &u.wv.wrow[px * K_DIM];
        for (int a = sub; a < NANG; a += 32) {
            float2 c = u.wv.cst[a];
            float t = fmaf(x, c.x, fmaf(y, c.y, 63.5f));
            t = fminf(fmaxf(t, 0.f), 127.f);
            float tf = fminf(floorf(t), 126.f);
            int   ti = (int)tf;
            float wt = t - tf;
            float src = ((float)a + 0.5f) * 0.0625f - 0.5f;
            src = fminf(fmaxf(src, 0.f), 7.f);
            float vf = floorf(src);
            int   v0 = (int)vf;
            int   v1 = v0 + 1 < NV ? v0 + 1 : NV - 1;
            float wa = src - vf;
            float wA0 = (1.f - wa) * OUT_SCALE;
            atomicAdd(&prow[v0 * W + ti],     wA0 * (1.f - wt));
            atomicAdd(&prow[v0 * W + ti + 1], wA0 * wt);
            if (v1 != v0) {
                float wA1 = wa * OUT_SCALE;
                atomicAdd(&prow[v1 * W + ti],     wA1 * (1.f - wt));
                atomicAdd(&prow[v1 * W + ti + 1], wA1 * wt);
            }
        }
        __syncthreads();
        // packed 2x f16 stores; block's 8192 elements are contiguous at wv + p0*K
        uint* wvu = (uint*)(wv + (size_t)p0 * K_DIM);
#pragma unroll
        for (int j = 0; j < 16; ++j) {
            int j2 = tid + 256 * j;
            float2 w2 = *(const float2*)&u.wv.wrow[j2 * 2];
            union { uint uu; struct { _Float16 lo, hi; } h; } pk;
            pk.h.lo = (_Float16)w2.x; pk.h.hi = (_Float16)w2.y;
            wvu[j2] = pk.uu;
        }
    }
}

// ---- kernel 2: 256x256-tile 8-phase pipelined GEMM ----
// Out[m][n] = sum_k Pf[m][k] * Wv[n][k].  M=2048, N=16384, K=1024.
// 512 threads = 8 waves (2M x 4N), per-wave 128x64 output, BK=64, NT=16.
// LDS 128 KiB: 2 buffers x (A 32K | B 32K).  XOR swizzle q^= row&7 on both
// write-source and read (glds dest stays linear).  One vmcnt(4) per K-tile.
// XCD swizzle: XCD x owns N-band [x*8, x*8+8) x all 8 m-tiles -> per-XCD L2
// fill = A(4MB, 8-block shared) + B-band(4MB, 8-block shared) = 8 MB.
#define NT 16

__device__ __forceinline__ void fencebar() {
    asm volatile("" ::: "memory");
    __builtin_amdgcn_s_barrier();
    asm volatile("" ::: "memory");
}

// Stage one half-tile (128 rows x 64 halfs = 16 KiB) of matrix G (row-major
// [rows][K_DIM]) into LDS region L (linear [256][64] halfs), rows h*128..h*128+127,
// K columns kt*64..kt*64+63.  2 glds16 per thread.  Global source is
// inverse-swizzled so reads can apply q ^= (row&7).
__device__ __forceinline__ void stage_half(const _Float16* __restrict__ G, int R0,
                                           int h, int kt, _Float16* L, int tid) {
#pragma unroll
    for (int r = 0; r < 2; ++r) {
        const int c   = r * 512 + tid;            // chunk 0..1023 (16 B each)
        const int row = (h << 7) + (c >> 3);
        const int q   = c & 7;
        const _Float16* src = G + (size_t)(R0 + row) * K_DIM + kt * 64
                                + ((q ^ (row & 7)) << 3);
        _Float16* dst = L + (h << 13) + ((r * 512 + (tid & 448)) << 3); // wave-uniform
        glds16(src, dst);
    }
}

__device__ __forceinline__ f16x8 frag(const _Float16* L, int row, int q) {
    return *(const f16x8*)(L + row * 64 + ((q ^ (row & 7)) << 3));
}

__global__ __launch_bounds__(512, 2)
void k_gemm(const _Float16* __restrict__ A,
            const _Float16* __restrict__ Bm,
            float* __restrict__ out) {
    __shared__ _Float16 lds[65536];   // 128 KiB
    const int tid  = threadIdx.x;
    const int lane = tid & 63, wid = tid >> 6;
    const int wm = wid >> 2, wn = wid & 3;
    const int fr = lane & 15, fg = lane >> 4;

    // bijective XCD swizzle (512 blocks % 8 == 0): XCD x owns n-tiles
    // [x*8, x*8+8) across all 8 m-tiles.
    const int flat = blockIdx.y * 64 + blockIdx.x;
    const int x    = flat & 7;         // XCD id (dispatch round-robin)
    const int idx  = flat >> 3;        // 0..63 within XCD
    const int m0 = (idx >> 3) * 256;
    const int n0 = (x * 8 + (idx & 7)) * 256;

    _Float16* const A0 = lds;
    _Float16* const B0 = lds + 16384;
    _Float16* const A1 = lds + 32768;
    _Float16* const B1 = lds + 49152;

    // prologue: tile0 all 4 halves + tile1 B-lo, A-lo  (12 loads/thread)
    stage_half(Bm, n0, 0, 0, B0, tid);
    stage_half(A,  m0, 0, 0, A0, tid);
    stage_half(Bm, n0, 1, 0, B0, tid);
    stage_half(A,  m0, 1, 0, A0, tid);
    stage_half(Bm, n0, 0, 1, B1, tid);
    stage_half(A,  m0, 0, 1, A1, tid);
    asm volatile("s_waitcnt vmcnt(4)" ::: "memory");  // tile0 landed; tile1 lo in flight
    fencebar();

    f32x4 acc[8][4] = {};
    f16x8 af[4][2], bf[4][2];
    const int ar = wm * 128 + fr;
    const int br = wn * 64 + fr;

    // per K-tile: 4 phases.  Stage slots (safety: issue only after the last
    // reader's barrier): P1->t+1 B-hi, P2->t+1 A-hi, P3->t+2 B-lo (B-lo of
    // buf[t&1] last read P2), P4->t+2 A-lo (A-lo last read P3).
    auto tile = [&](int t, _Float16* Ab, _Float16* Bb, _Float16* An, _Float16* Bn)
        __attribute__((always_inline)) {
        // ---- P1: read A m0-3 (8) + B n0-1 (4); MFMA m0-3 x n0-1 ----
#pragma unroll
        for (int i = 0; i < 4; ++i) {
            af[i][0] = frag(Ab, ar + i * 16, fg);
            af[i][1] = frag(Ab, ar + i * 16, 4 + fg);
        }
#pragma unroll
        for (int j = 0; j < 2; ++j) {
            bf[j][0] = frag(Bb, br + j * 16, fg);
            bf[j][1] = frag(Bb, br + j * 16, 4 + fg);
        }
        if (t + 1 < NT) stage_half(Bm, n0, 1, t + 1, Bn, tid);
        fencebar();
        asm volatile("s_waitcnt lgkmcnt(0)" ::: "memory");
        __builtin_amdgcn_sched_barrier(0);
        __builtin_amdgcn_s_setprio(1);
#pragma unroll
        for (int i = 0; i < 4; ++i)
#pragma unroll
            for (int j = 0; j < 2; ++j) {
                acc[i][j] = __builtin_amdgcn_mfma_f32_16x16x32_f16(af[i][0], bf[j][0], acc[i][j], 0, 0, 0);
                acc[i][j] = __builtin_amdgcn_mfma_f32_16x16x32_f16(af[i][1], bf[j][1], acc[i][j], 0, 0, 0);
            }
        __builtin_amdgcn_s_setprio(0);
        fencebar();
        // ---- P2: read B n2-3 (4); MFMA m0-3 x n2-3 ----
#pragma unroll
        for (int j = 2; j < 4; ++j) {
            bf[j][0] = frag(Bb, br + j * 16, fg);
            bf[j][1] = frag(Bb, br + j * 16, 4 + fg);
        }
        if (t + 1 < NT) stage_half(A, m0, 1, t + 1, An, tid);
        fencebar();
        asm volatile("s_waitcnt lgkmcnt(0)" ::: "memory");
        __builtin_amdgcn_sched_barrier(0);
        __builtin_amdgcn_s_setprio(1);
#pragma unroll
        for (int i = 0; i < 4; ++i)
#pragma unroll
            for (int j = 2; j < 4; ++j) {
                acc[i][j] = __builtin_amdgcn_mfma_f32_16x16x32_f16(af[i][0], bf[j][0], acc[i][j], 0, 0, 0);
                acc[i][j] = __builtin_amdgcn_mfma_f32_16x16x32_f16(af[i][1], bf[j][1], acc[i][j], 0, 0, 0);
            }
        __builtin_amdgcn_s_setprio(0);
        fencebar();
        // ---- P3: read A m4-7 (8); MFMA m4-7 x n2-3 ----
#pragma unroll
        for (int i = 0; i < 4; ++i) {
            af[i][0] = frag(Ab, ar + 64 + i * 16, fg);
            af[i][1] = frag(Ab, ar + 64 + i * 16, 4 + fg);
        }
        if (t + 2 < NT) stage_half(Bm, n0, 0, t + 2, Bb, tid);
        fencebar();
        asm volatile("s_waitcnt lgkmcnt(0)" ::: "memory");
        __builtin_amdgcn_sched_barrier(0);
        __builtin_amdgcn_s_setprio(1);
#pragma unroll
        for (int i = 0; i < 4; ++i)
#pragma unroll
            for (int j = 2; j < 4; ++j) {
                acc[4 + i][j] = __builtin_amdgcn_mfma_f32_16x16x32_f16(af[i][0], bf[j][0], acc[4 + i][j], 0, 0, 0);
                acc[4 + i][j] = __builtin_amdgcn_mfma_f32_16x16x32_f16(af[i][1], bf[j][1], acc[4 + i][j], 0, 0, 0);
            }
        __builtin_amdgcn_s_setprio(0);
        fencebar();
        // ---- P4: no reads; MFMA m4-7 x n0-1; counted tile-end wait ----
        if (t + 2 < NT) stage_half(A, m0, 0, t + 2, Ab, tid);
        fencebar();
        __builtin_amdgcn_s_setprio(1);
#pragma unroll
        for (int i = 0; i < 4; ++i)
#pragma unroll
            for (int j = 0; j < 2; ++j) {
                acc[4 + i][j] = __builtin_amdgcn_mfma_f32_16x16x32_f16(af[i][0], bf[j][0], acc[4 + i][j], 0, 0, 0);
                acc[4 + i][j] = __builtin_amdgcn_mfma_f32_16x16x32_f16(af[i][1], bf[j][1], acc[4 + i][j], 0, 0, 0);
            }
        __builtin_amdgcn_s_setprio(0);
        if (t + 2 < NT)      asm volatile("s_waitcnt vmcnt(4)" ::: "memory");
        else if (t + 1 < NT) asm volatile("s_waitcnt vmcnt(0)" ::: "memory");
        fencebar();
    };

    for (int tt = 0; tt < NT; tt += 2) {
        tile(tt,     A0, B0, A1, B1);
        tile(tt + 1, A1, B1, A0, B0);
    }

    // epilogue: C/D col = fr (n), row = fg*4 + rr (m within 16)
#pragma unroll
    for (int i = 0; i < 8; ++i) {
#pragma unroll
        for (int j = 0; j < 4; ++j) {
            const int m = m0 + wm * 128 + i * 16 + fg * 4;
            const int n = n0 + wn * 64 + j * 16 + fr;
            float* op = out + (size_t)m * NPIX + n;
#pragma unroll
            for (int rr = 0; rr < 4; ++rr)
                op[(size_t)rr * NPIX] = acc[i][j][rr];
        }
    }
}

extern "C" void kernel_launch(void* const* d_in, const int* in_sizes, int n_in,
                              void* d_out, int out_size, void* d_ws, size_t ws_size,
                              hipStream_t stream) {
    _Float16*   pf = (_Float16*)((char*)d_ws + PF_OFF);
    _Float16*   wv = (_Float16*)((char*)d_ws + WV_OFF);

    Ptrs8 in;
    for (int i = 0; i < NV; ++i) in.p[i] = (const float*)d_in[i];

    k_prep<<<PREP_FG_BLOCKS + NPIX / 8, 256, 0, stream>>>(in, pf, wv);
    dim3 grid(NPIX / 256, NROWS / 256);   // 64 x 8 = 512 blocks
    k_gemm<<<grid, 512, 0, stream>>>(pf, wv, (float*)d_out);
}